// Round 9
// baseline (213.303 us; speedup 1.0000x reference)
//
#include <hip/hip_runtime.h>
#include <math.h>

#define SEQ 2048
#define NH 12
#define HD 64
#define DIM 768

typedef _Float16 half_t;
typedef _Float16 f16x8 __attribute__((ext_vector_type(8)));
typedef _Float16 f16x4 __attribute__((ext_vector_type(4)));
typedef float f32x4 __attribute__((ext_vector_type(4)));

__device__ __forceinline__ void dma16(const half_t* g, half_t* l) {
  __builtin_amdgcn_global_load_lds(
      (const __attribute__((address_space(1))) unsigned int*)g,
      (__attribute__((address_space(3))) unsigned int*)l, 16, 0, 0);
}

// ---------------------------------------------------------------------------
// Kernel 0: fp32 -> fp16. x16/w16 get the 8-half chunk XOR swizzle baked into
// the GLOBAL layout (DMA-stageable). wp16 plain.
// ---------------------------------------------------------------------------
__global__ __launch_bounds__(256) void cvt_f32_f16(
    const float* __restrict__ a, const float* __restrict__ b,
    const float* __restrict__ c, half_t* __restrict__ a16,
    half_t* __restrict__ b16, half_t* __restrict__ c16) {
  const size_t NA = 786432, NB = 442368;  // float4 counts: x, qkv_w
  size_t i = (size_t)blockIdx.x * 256 + threadIdx.x;
  if (i < NA + NB) {
    const float* src = (i < NA) ? a : b;
    half_t* dst = (i < NA) ? a16 : b16;
    size_t off = (i < NA) ? i : i - NA;
    float4 v = *(const float4*)&src[off * 4];
    f16x4 h;
    h[0] = (half_t)v.x; h[1] = (half_t)v.y; h[2] = (half_t)v.z; h[3] = (half_t)v.w;
    int row = (int)((off * 4) / DIM);
    int col = (int)((off * 4) % DIM);
    int sc = col ^ ((row & 7) << 3);
    *(f16x4*)&dst[(size_t)row * DIM + sc] = h;
  } else {
    size_t off = i - NA - NB;
    float4 v = *(const float4*)&c[off * 4];
    f16x4 h;
    h[0] = (half_t)v.x; h[1] = (half_t)v.y; h[2] = (half_t)v.z; h[3] = (half_t)v.w;
    *(f16x4*)&c16[off * 4] = h;
  }
}

// ---------------------------------------------------------------------------
// Kernel 1: qkv GEMM — DMA double-buffered staging from pre-swizzled x16/w16.
// q,k -> fp32 d-major; v -> chunked+swizzled fp16 blocks.
// ---------------------------------------------------------------------------
__global__ __launch_bounds__(256) void gemm_qkv_f16(
    const half_t* __restrict__ xs, const half_t* __restrict__ ws,
    float* __restrict__ qT, float* __restrict__ kT, half_t* __restrict__ vb) {
  __shared__ half_t As[2][128][64];
  __shared__ half_t Bs[2][128][64];
  const int tid = threadIdx.x;
  const int lane = tid & 63, wave = tid >> 6;
  const int quad = lane >> 4, l16 = lane & 15;
  const int wr = wave >> 1, wc = wave & 1;
  const int row0 = blockIdx.y * 128;
  const int col0 = blockIdx.x * 128;
  const int rl = lane >> 3, ch = lane & 7;

#pragma unroll
  for (int i = 0; i < 4; i++) {
    int ins = wave * 4 + i;
    dma16(xs + (size_t)(row0 + ins * 8 + rl) * DIM + ch * 8, &As[0][ins * 8][0]);
    dma16(ws + (size_t)(col0 + ins * 8 + rl) * DIM + ch * 8, &Bs[0][ins * 8][0]);
  }

  f32x4 acc[4][4] = {};

  for (int c = 0; c < 12; c++) {
    const int cur = c & 1;
    __syncthreads();
    if (c < 11) {
      int k0 = (c + 1) * 64;
#pragma unroll
      for (int i = 0; i < 4; i++) {
        int ins = wave * 4 + i;
        dma16(xs + (size_t)(row0 + ins * 8 + rl) * DIM + k0 + ch * 8,
              &As[1 - cur][ins * 8][0]);
        dma16(ws + (size_t)(col0 + ins * 8 + rl) * DIM + k0 + ch * 8,
              &Bs[1 - cur][ins * 8][0]);
      }
    }
#pragma unroll
    for (int ks = 0; ks < 2; ks++) {
      f16x8 af[4], bf[4];
#pragma unroll
      for (int i = 0; i < 4; i++) {
        int rr = wr * 64 + i * 16 + l16;
        af[i] = *(const f16x8*)&As[cur][rr][((ks * 4 + quad) ^ (rr & 7)) << 3];
      }
#pragma unroll
      for (int j = 0; j < 4; j++) {
        int rr = wc * 64 + j * 16 + l16;
        bf[j] = *(const f16x8*)&Bs[cur][rr][((ks * 4 + quad) ^ (rr & 7)) << 3];
      }
#pragma unroll
      for (int i = 0; i < 4; i++)
#pragma unroll
        for (int j = 0; j < 4; j++)
          acc[i][j] = __builtin_amdgcn_mfma_f32_16x16x32_f16(af[i], bf[j], acc[i][j], 0, 0, 0);
    }
  }

  const int fbase = col0 + wc * 64;
#pragma unroll
  for (int i = 0; i < 4; i++) {
    int n = row0 + wr * 64 + i * 16 + quad * 4;
    int b = n >> 11, nn = n & (SEQ - 1);
#pragma unroll
    for (int j = 0; j < 4; j++) {
      int f = fbase + j * 16 + l16;
      if (col0 < 1536) {
        float* dst = (col0 < 768) ? qT : kT;
        int fo = (col0 < 768) ? f : f - 768;
        *(f32x4*)&dst[((size_t)(b * 768 + fo)) * SEQ + nn] = acc[i][j];
      } else {
        int fo = f - 1536;
        int h = fo >> 6, d = fo & 63;
        int bh = b * NH + h;
        int chn = nn >> 6, cw = (nn & 63) >> 3, sub = nn & 7;
        f16x4 hv;
#pragma unroll
        for (int r = 0; r < 4; r++) hv[r] = (half_t)acc[i][j][r];
        *(f16x4*)&vb[((((size_t)bh * 32 + chn) * 64 + d) << 6) +
                     (((cw ^ (d & 7)) << 3) + sub)] = hv;
      }
    }
  }
}

// ---------------------------------------------------------------------------
// Kernel 2: spectral filter. Forward DIF -> pointwise even filter at bitrev
// positions -> inverse DIT. Q output pre-scaled by 0.125*log2(e) so the
// attention kernel's exp argument is the raw MFMA output.
// ---------------------------------------------------------------------------
__device__ __forceinline__ void fft2048_dif_fwd(float* re, float* im, int tid) {
  for (int M = 2048; M >= 8; M >>= 2) {
    const int q = M >> 2;
    const float ang = -6.283185307179586f / (float)M;
#pragma unroll 2
    for (int g = tid; g < 512; g += 256) {
      int j = g & (q - 1);
      int base = ((g & ~(q - 1)) << 2) | j;
      float s1, c1;
      __sincosf(ang * (float)j, &s1, &c1);
      float c2 = c1 * c1 - s1 * s1, s2 = 2.0f * c1 * s1;
      float Ar = re[base],         Ai = im[base];
      float Br = re[base + q],     Bi = im[base + q];
      float Cr = re[base + 2*q],   Ci = im[base + 2*q];
      float Dr = re[base + 3*q],   Di = im[base + 3*q];
      float A1r = Ar + Cr, A1i = Ai + Ci;
      float t1r = Ar - Cr, t1i = Ai - Ci;
      float C1r = c1 * t1r - s1 * t1i, C1i = c1 * t1i + s1 * t1r;
      float B1r = Br + Dr, B1i = Bi + Di;
      float t2r = Br - Dr, t2i = Bi - Di;
      float u2r = c1 * t2r - s1 * t2i, u2i = c1 * t2i + s1 * t2r;
      float D1r = u2i, D1i = -u2r;
      re[base]         = A1r + B1r; im[base]         = A1i + B1i;
      float t3r = A1r - B1r, t3i = A1i - B1i;
      re[base + q]     = c2 * t3r - s2 * t3i;
      im[base + q]     = c2 * t3i + s2 * t3r;
      re[base + 2*q]   = C1r + D1r; im[base + 2*q]   = C1i + D1i;
      float t4r = C1r - D1r, t4i = C1i - D1i;
      re[base + 3*q]   = c2 * t4r - s2 * t4i;
      im[base + 3*q]   = c2 * t4i + s2 * t4r;
    }
    __syncthreads();
  }
#pragma unroll 2
  for (int i = tid; i < 1024; i += 256) {
    float ar = re[2*i], ai = im[2*i], br = re[2*i+1], bi = im[2*i+1];
    re[2*i]   = ar + br; im[2*i]   = ai + bi;
    re[2*i+1] = ar - br; im[2*i+1] = ai - bi;
  }
  __syncthreads();
}

__device__ __forceinline__ void fft2048_dit_inv(float* re, float* im, int tid) {
  for (int L = 2; L <= 512; L <<= 2) {
    const int h = L >> 1;
    const float ang = 3.14159265358979f / (float)L;
#pragma unroll 2
    for (int g = tid; g < SEQ / 4; g += 256) {
      int p = g & (h - 1);
      int i0 = ((g & ~(h - 1)) << 2) | p;
      float s2, c2;
      __sincosf(ang * (float)p, &s2, &c2);
      float c1 = c2 * c2 - s2 * s2, s1 = 2.0f * c2 * s2;
      float ar = re[i0],         ai = im[i0];
      float br = re[i0 + h],     bi = im[i0 + h];
      float cr = re[i0 + L],     ci = im[i0 + L];
      float dr = re[i0 + L + h], di = im[i0 + L + h];
      float t1r = c1 * br - s1 * bi, t1i = c1 * bi + s1 * br;
      float a1r = ar + t1r, a1i = ai + t1i;
      float b1r = ar - t1r, b1i = ai - t1i;
      float t2r = c1 * dr - s1 * di, t2i = c1 * di + s1 * dr;
      float e1r = cr + t2r, e1i = ci + t2i;
      float d1r = cr - t2r, d1i = ci - t2i;
      float ur = c2 * e1r - s2 * e1i, ui = c2 * e1i + s2 * e1r;
      float vr = c2 * d1r - s2 * d1i, vi = c2 * d1i + s2 * d1r;
      float wr = -vi, wi = vr;
      re[i0]         = a1r + ur; im[i0]         = a1i + ui;
      re[i0 + L]     = a1r - ur; im[i0 + L]     = a1i - ui;
      re[i0 + h]     = b1r + wr; im[i0 + h]     = b1i + wi;
      re[i0 + L + h] = b1r - wr; im[i0 + L + h] = b1i - wi;
    }
    __syncthreads();
  }
  {
    const float ang = 6.283185307179586f / 2048.0f;
#pragma unroll 2
    for (int j = tid; j < 1024; j += 256) {
      float s, c;
      __sincosf(ang * (float)j, &s, &c);
      float x0r = re[j], x0i = im[j], x1r = re[j + 1024], x1i = im[j + 1024];
      float tr = c * x1r - s * x1i, ti = c * x1i + s * x1r;
      re[j] = x0r + tr;        im[j] = x0i + ti;
      re[j + 1024] = x0r - tr; im[j + 1024] = x0i - ti;
    }
    __syncthreads();
  }
}

__global__ __launch_bounds__(256) void fft_filter(
    const float* __restrict__ qT, const float* __restrict__ kT,
    half_t* __restrict__ qh, half_t* __restrict__ kh,
    const float* __restrict__ freq_params) {
  __shared__ float re[SEQ];
  __shared__ float im[SEQ];
  const int tid = threadIdx.x;
  const int idx = blockIdx.x;
  const int h = (idx >> 6) % NH;
  const float* qrow = qT + (size_t)idx * SEQ;
  const float* krow = kT + (size_t)idx * SEQ;

  for (int n = tid; n < SEQ; n += 256) { re[n] = qrow[n]; im[n] = krow[n]; }
  __syncthreads();
  fft2048_dif_fwd(re, im, tid);

  const float fp = freq_params[h];
  const float sig = 1.0f / (1.0f + __expf(-fp));
  const float cutoff = floorf((float)SEQ * sig);

#pragma unroll 2
  for (int p = tid; p < SEQ; p += 256) {
    int n = (int)(__brev((unsigned)p) >> 21);
    int m = (SEQ - n) & (SEQ - 1);
    float r1 = (float)n - cutoff;
    float r2 = (float)m - cutoff;
    float A1 = (r1 >= 0.0f) ? __expf(-r1 * (1.0f / 512.0f)) : 1.0f;
    float A2 = (r2 >= 0.0f) ? __expf(-r2 * (1.0f / 512.0f)) : 1.0f;
    float Ae = 0.5f * (A1 + A2);
    re[p] *= Ae; im[p] *= Ae;
  }
  __syncthreads();

  fft2048_dit_inv(re, im, tid);

  const float invq = (1.0f / (float)SEQ) * 0.18033688011112042f;  // /N * 0.125*log2e
  const float inv = 1.0f / (float)SEQ;
  half_t* qo = qh + (size_t)idx * SEQ;
  half_t* ko = kh + (size_t)idx * SEQ;
  for (int n = tid; n < SEQ; n += 256) {
    qo[n] = (half_t)(re[n] * invq);
    ko[n] = (half_t)(im[n] * inv);
  }
}

// ---------------------------------------------------------------------------
// Kernel 3: transpose K: fp16 d-major -> n-major with chunk XOR swizzle.
// ---------------------------------------------------------------------------
__global__ __launch_bounds__(256) void transpose_k16(
    const half_t* __restrict__ kh, half_t* __restrict__ kA) {
  __shared__ half_t tl[64][65];
  const int t = threadIdx.x;
  const int N0 = blockIdx.x * 64;
  const int bh = blockIdx.y;
#pragma unroll
  for (int i = 0; i < 2; i++) {
    int idx = i * 256 + t;
    int d = idx >> 3, n8 = (idx & 7) << 3;
    f16x8 v = *(const f16x8*)&kh[((size_t)(bh * 64 + d)) * SEQ + N0 + n8];
#pragma unroll
    for (int j = 0; j < 8; j++) tl[d][n8 + j] = v[j];
  }
  __syncthreads();
#pragma unroll
  for (int i = 0; i < 2; i++) {
    int idx = i * 256 + t;
    int nl = idx >> 3, chunk = idx & 7;
    f16x8 v;
#pragma unroll
    for (int j = 0; j < 8; j++) v[j] = tl[chunk * 8 + j][nl];
    *(f16x8*)&kA[((size_t)(bh * SEQ + N0 + nl)) * 64 + (chunk ^ (nl & 7)) * 8] = v;
  }
}

// ---------------------------------------------------------------------------
// Kernel 4: attention v8. Grid 1536 (32 q-tiles of 64 x 24 bh x 2 mhalf):
// 5 blocks/CU (LDS-capped) for latency hiding. Raw v_exp_f32 via
// __builtin_amdgcn_exp2f (scale folded into q_h, shift dropped — cancels in
// normalization), K/V DMA double-buffered, one barrier per chunk, L row-sums
// on the MFMA pipe.
// ---------------------------------------------------------------------------
__global__ __launch_bounds__(256) void attention_v8(
    const half_t* __restrict__ q_h, const half_t* __restrict__ kA,
    const half_t* __restrict__ vb, float* __restrict__ part0,
    float* __restrict__ part1, float* __restrict__ Lp0,
    float* __restrict__ Lp1) {
  __shared__ half_t ks[2][64][64];
  __shared__ half_t vs[2][64][64];
  const int t = threadIdx.x;
  const int lane = t & 63, wave = t >> 6;
  const int quad = lane >> 4, l16 = lane & 15;
  const int id = blockIdx.x;
  const int bh = (id & 7) * 3 + ((id >> 3) % 3);   // 3 bh per XCD
  const int rest = id / 24;                        // 0..63
  const int qt = rest >> 1, mh = rest & 1;
  const int N0 = qt * 64;
  float* part = mh ? part1 : part0;
  float* Lp = mh ? Lp1 : Lp0;
  const half_t* kbase = kA + ((size_t)bh * SEQ + mh * 1024) * 64;
  const half_t* vbase = vb + (((size_t)bh * 32 + mh * 16) << 12);
  const half_t* qb = q_h + (size_t)bh * 64 * SEQ;

  // Q fragment gathered from d-major (B-frag: n on lanes, d in regs)
  f16x8 qlo, qhi;
  {
    int n = N0 + wave * 16 + l16;
#pragma unroll
    for (int e = 0; e < 8; e++) {
      qlo[e] = qb[(size_t)(quad * 8 + e) * SEQ + n];
      qhi[e] = qb[(size_t)(32 + quad * 8 + e) * SEQ + n];
    }
  }

  // prologue: DMA chunk 0 into buffer 0
#pragma unroll
  for (int i = 0; i < 2; i++) {
    int ins = wave * 2 + i;
    dma16(kbase + ins * 512 + lane * 8, &ks[0][ins * 8][0]);
    dma16(vbase + ins * 512 + lane * 8, &vs[0][ins * 8][0]);
  }

  f32x4 acc[4] = {};
  f32x4 accL = {};
  f16x4 ones;
  ones[0] = (half_t)1.0f; ones[1] = (half_t)1.0f;
  ones[2] = (half_t)1.0f; ones[3] = (half_t)1.0f;

  for (int c = 0; c < 16; c++) {
    const int cur = c & 1;
    __syncthreads();

    if (c < 15) {
      const int cn = c + 1;
#pragma unroll
      for (int i = 0; i < 2; i++) {
        int ins = wave * 2 + i;
        dma16(kbase + (size_t)cn * 4096 + ins * 512 + lane * 8,
              &ks[1 - cur][ins * 8][0]);
        dma16(vbase + (size_t)cn * 4096 + ins * 512 + lane * 8,
              &vs[1 - cur][ins * 8][0]);
      }
    }

    // QK^T (S^T layout) + exp2 (raw score already includes 0.125*log2e)
    f16x4 pf[4];
#pragma unroll
    for (int j = 0; j < 4; j++) {
      int row = j * 16 + l16;
      int sw = row & 7;
      f16x8 klo = *(const f16x8*)&ks[cur][row][(quad ^ sw) * 8];
      f16x8 khi = *(const f16x8*)&ks[cur][row][((quad + 4) ^ sw) * 8];
      f32x4 s = {};
      s = __builtin_amdgcn_mfma_f32_16x16x32_f16(klo, qlo, s, 0, 0, 0);
      s = __builtin_amdgcn_mfma_f32_16x16x32_f16(khi, qhi, s, 0, 0, 0);
      float e0 = __builtin_amdgcn_exp2f(s[0]);
      float e1 = __builtin_amdgcn_exp2f(s[1]);
      float e2 = __builtin_amdgcn_exp2f(s[2]);
      float e3 = __builtin_amdgcn_exp2f(s[3]);
      auto plo = __builtin_amdgcn_cvt_pkrtz(e0, e1);
      auto phi = __builtin_amdgcn_cvt_pkrtz(e2, e3);
      pf[j][0] = (half_t)plo[0]; pf[j][1] = (half_t)plo[1];
      pf[j][2] = (half_t)phi[0]; pf[j][3] = (half_t)phi[1];
    }

    // L on MFMA pipe + PV
#pragma unroll
    for (int j = 0; j < 4; j++) {
      accL = __builtin_amdgcn_mfma_f32_16x16x16f16(pf[j], ones, accL, 0, 0, 0);
#pragma unroll
      for (int dt = 0; dt < 4; dt++) {
        int d = dt * 16 + l16;
        int cc = ((2 * j + (quad >> 1)) ^ (d & 7));
        f16x4 bv = *(const f16x4*)&vs[cur][d][cc * 8 + (quad & 1) * 4];
        acc[dt] = __builtin_amdgcn_mfma_f32_16x16x16f16(pf[j], bv, acc[dt], 0, 0, 0);
      }
    }
  }

  if (l16 == 0) {
#pragma unroll
    for (int r = 0; r < 4; r++)
      Lp[(size_t)bh * SEQ + N0 + wave * 16 + quad * 4 + r] = accL[r];
  }
#pragma unroll
  for (int dt = 0; dt < 4; dt++) {
#pragma unroll
    for (int r = 0; r < 4; r++) {
      int n = N0 + wave * 16 + quad * 4 + r;
      part[((size_t)bh * SEQ + n) * 64 + dt * 16 + l16] = acc[dt][r];
    }
  }
}

// ---------------------------------------------------------------------------
// Kernel 5: proj GEMM with FUSED combine: A is staged directly from the fp32
// partials (p0+p1)/(L0+L1), converted to fp16 on the fly. out = A@W^T + bias.
// ---------------------------------------------------------------------------
__global__ __launch_bounds__(256) void gemm_proj_fused(
    const float* __restrict__ p0, const float* __restrict__ p1,
    const float* __restrict__ L0, const float* __restrict__ L1,
    const half_t* __restrict__ w, const float* __restrict__ bias,
    float* __restrict__ out) {
  __shared__ half_t As[128][64];
  __shared__ half_t Bs[128][64];
  const int tid = threadIdx.x;
  const int lane = tid & 63, wave = tid >> 6;
  const int quad = lane >> 4, l16 = lane & 15;
  const int wr = wave >> 1, wc = wave & 1;
  const int row0 = blockIdx.y * 128;
  const int col0 = blockIdx.x * 128;
  const int srow = tid >> 3;
  const int schk = tid & 7;

  f32x4 acc[4][4] = {};

  for (int k0 = 0; k0 < DIM; k0 += 64) {
    // A staged from partials: c-range [k0+schk*8, +8) lies in one head.
    const int cbase = k0 + schk * 8;
    const int h = cbase >> 6, d0 = cbase & 63;
    f16x8 av[4];
    f16x8 bv[4];
#pragma unroll
    for (int p = 0; p < 4; p++) {
      int mg = row0 + srow + p * 32;
      int b = mg >> 11, nn = mg & (SEQ - 1);
      size_t lrow = (size_t)(b * NH + h) * SEQ + nn;
      size_t base = lrow * 64 + d0;
      f32x4 a0 = *(const f32x4*)&p0[base];
      f32x4 a1 = *(const f32x4*)&p0[base + 4];
      f32x4 b0 = *(const f32x4*)&p1[base];
      f32x4 b1 = *(const f32x4*)&p1[base + 4];
      float invl = 1.0f / (L0[lrow] + L1[lrow]);
#pragma unroll
      for (int e = 0; e < 4; e++) {
        av[p][e]     = (half_t)((a0[e] + b0[e]) * invl);
        av[p][e + 4] = (half_t)((a1[e] + b1[e]) * invl);
      }
      bv[p] = *(const f16x8*)&w[(size_t)(col0 + srow + p * 32) * DIM + k0 + schk * 8];
    }
    __syncthreads();
#pragma unroll
    for (int p = 0; p < 4; p++) {
      int r = srow + p * 32;
      int cs = ((schk ^ (r & 7)) << 3);
      *(f16x8*)&As[r][cs] = av[p];
      *(f16x8*)&Bs[r][cs] = bv[p];
    }
    __syncthreads();
#pragma unroll
    for (int ks = 0; ks < 2; ks++) {
      f16x8 af[4], bf[4];
#pragma unroll
      for (int i = 0; i < 4; i++) {
        int rr = wr * 64 + i * 16 + l16;
        af[i] = *(const f16x8*)&As[rr][((ks * 4 + quad) ^ (rr & 7)) << 3];
      }
#pragma unroll
      for (int j = 0; j < 4; j++) {
        int rr = wc * 64 + j * 16 + l16;
        bf[j] = *(const f16x8*)&Bs[rr][((ks * 4 + quad) ^ (rr & 7)) << 3];
      }
#pragma unroll
      for (int i = 0; i < 4; i++)
#pragma unroll
        for (int j = 0; j < 4; j++)
          acc[i][j] = __builtin_amdgcn_mfma_f32_16x16x32_f16(af[i], bf[j], acc[i][j], 0, 0, 0);
    }
  }

#pragma unroll
  for (int i = 0; i < 4; i++) {
    int m = row0 + wr * 64 + i * 16 + quad * 4;
#pragma unroll
    for (int j = 0; j < 4; j++) {
      int f = col0 + wc * 64 + j * 16 + l16;
      float bj = bias[f];
#pragma unroll
      for (int r = 0; r < 4; r++)
        out[(size_t)(m + r) * DIM + f] = acc[i][j][r] + bj;
    }
  }
}

// ---------------------------------------------------------------------------
extern "C" void kernel_launch(void* const* d_in, const int* in_sizes, int n_in,
                              void* d_out, int out_size, void* d_ws, size_t ws_size,
                              hipStream_t stream) {
  (void)in_sizes; (void)n_in; (void)out_size; (void)ws_size;
  const float* x      = (const float*)d_in[0];
  const float* qkv_w  = (const float*)d_in[1];
  const float* proj_w = (const float*)d_in[2];
  const float* proj_b = (const float*)d_in[3];
  const float* freq   = (const float*)d_in[4];
  float* out = (float*)d_out;
  char* ws = (char*)d_ws;

  // Workspace (bytes):
  //  wp16 [0, 1179648)                   plain fp16 proj_w
  //  qT   [1179648, 13762560)  fp32  ->  part0 after fft
  //  kT   [13762560, 26345472) fp32  ->  part1 after fft
  //  v_blk[26345472, 32636928) fp16      chunked+swizzled
  //  x16  [32636928, 38928384) fp16 swz -> k_h after gemm
  //  w16  [38928384, 42467328) fp16 swz -> Lp0/Lp1 after gemm
  //  q_h  [42467328, 48758784) fp16      (d-major, q pre-scaled)
  //  kA (n-major swizzled): d_out[0 : 6291456) — overwritten by proj at end
  half_t* wp16 = (half_t*)(ws);
  float*  qT   = (float*)(ws + 1179648);
  float*  kT   = (float*)(ws + 13762560);
  half_t* v_b  = (half_t*)(ws + 26345472);
  half_t* x16  = (half_t*)(ws + 32636928);
  half_t* w16  = (half_t*)(ws + 38928384);
  half_t* q_h  = (half_t*)(ws + 42467328);
  half_t* k_h  = (half_t*)(ws + 32636928);
  float*  part0 = (float*)(ws + 1179648);
  float*  part1 = (float*)(ws + 13762560);
  float*  Lp0  = (float*)(ws + 38928384);
  float*  Lp1  = (float*)(ws + 38928384 + 196608);
  half_t* kA   = (half_t*)d_out;

  cvt_f32_f16<<<5376, 256, 0, stream>>>(x, qkv_w, proj_w, x16, w16, wp16);
  gemm_qkv_f16<<<dim3(18, 32), 256, 0, stream>>>(x16, w16, qT, kT, v_b);
  fft_filter<<<1536, 256, 0, stream>>>(qT, kT, q_h, k_h, freq);
  transpose_k16<<<dim3(32, 24), 256, 0, stream>>>(k_h, kA);
  attention_v8<<<1536, 256, 0, stream>>>(q_h, kA, v_b, part0, part1, Lp0, Lp1);
  gemm_proj_fused<<<dim3(6, 32), 256, 0, stream>>>(part0, part1, Lp0, Lp1, wp16, proj_b, out);
}

// Round 10
// 200.595 us; speedup vs baseline: 1.0634x; 1.0634x over previous
//
#include <hip/hip_runtime.h>
#include <math.h>

#define SEQ 2048
#define NH 12
#define HD 64
#define DIM 768

typedef _Float16 half_t;
typedef _Float16 f16x8 __attribute__((ext_vector_type(8)));
typedef _Float16 f16x4 __attribute__((ext_vector_type(4)));
typedef float f32x4 __attribute__((ext_vector_type(4)));

__device__ __forceinline__ void dma16(const half_t* g, half_t* l) {
  __builtin_amdgcn_global_load_lds(
      (const __attribute__((address_space(1))) unsigned int*)g,
      (__attribute__((address_space(3))) unsigned int*)l, 16, 0, 0);
}

// ---------------------------------------------------------------------------
// Kernel 0: fp32 -> fp16. x16/w16 get the 8-half chunk XOR swizzle baked into
// the GLOBAL layout (DMA-stageable). wp16 plain.
// ---------------------------------------------------------------------------
__global__ __launch_bounds__(256) void cvt_f32_f16(
    const float* __restrict__ a, const float* __restrict__ b,
    const float* __restrict__ c, half_t* __restrict__ a16,
    half_t* __restrict__ b16, half_t* __restrict__ c16) {
  const size_t NA = 786432, NB = 442368;  // float4 counts: x, qkv_w
  size_t i = (size_t)blockIdx.x * 256 + threadIdx.x;
  if (i < NA + NB) {
    const float* src = (i < NA) ? a : b;
    half_t* dst = (i < NA) ? a16 : b16;
    size_t off = (i < NA) ? i : i - NA;
    float4 v = *(const float4*)&src[off * 4];
    f16x4 h;
    h[0] = (half_t)v.x; h[1] = (half_t)v.y; h[2] = (half_t)v.z; h[3] = (half_t)v.w;
    int row = (int)((off * 4) / DIM);
    int col = (int)((off * 4) % DIM);
    int sc = col ^ ((row & 7) << 3);
    *(f16x4*)&dst[(size_t)row * DIM + sc] = h;
  } else {
    size_t off = i - NA - NB;
    float4 v = *(const float4*)&c[off * 4];
    f16x4 h;
    h[0] = (half_t)v.x; h[1] = (half_t)v.y; h[2] = (half_t)v.z; h[3] = (half_t)v.w;
    *(f16x4*)&c16[off * 4] = h;
  }
}

// ---------------------------------------------------------------------------
// Kernel 1: qkv GEMM — DMA double-buffered staging from pre-swizzled x16/w16.
// q,k -> fp32 d-major; v -> chunked+swizzled fp16 blocks.
// ---------------------------------------------------------------------------
__global__ __launch_bounds__(256) void gemm_qkv_f16(
    const half_t* __restrict__ xs, const half_t* __restrict__ ws,
    float* __restrict__ qT, float* __restrict__ kT, half_t* __restrict__ vb) {
  __shared__ half_t As[2][128][64];
  __shared__ half_t Bs[2][128][64];
  const int tid = threadIdx.x;
  const int lane = tid & 63, wave = tid >> 6;
  const int quad = lane >> 4, l16 = lane & 15;
  const int wr = wave >> 1, wc = wave & 1;
  const int row0 = blockIdx.y * 128;
  const int col0 = blockIdx.x * 128;
  const int rl = lane >> 3, ch = lane & 7;

#pragma unroll
  for (int i = 0; i < 4; i++) {
    int ins = wave * 4 + i;
    dma16(xs + (size_t)(row0 + ins * 8 + rl) * DIM + ch * 8, &As[0][ins * 8][0]);
    dma16(ws + (size_t)(col0 + ins * 8 + rl) * DIM + ch * 8, &Bs[0][ins * 8][0]);
  }

  f32x4 acc[4][4] = {};

  for (int c = 0; c < 12; c++) {
    const int cur = c & 1;
    __syncthreads();
    if (c < 11) {
      int k0 = (c + 1) * 64;
#pragma unroll
      for (int i = 0; i < 4; i++) {
        int ins = wave * 4 + i;
        dma16(xs + (size_t)(row0 + ins * 8 + rl) * DIM + k0 + ch * 8,
              &As[1 - cur][ins * 8][0]);
        dma16(ws + (size_t)(col0 + ins * 8 + rl) * DIM + k0 + ch * 8,
              &Bs[1 - cur][ins * 8][0]);
      }
    }
#pragma unroll
    for (int ks = 0; ks < 2; ks++) {
      f16x8 af[4], bf[4];
#pragma unroll
      for (int i = 0; i < 4; i++) {
        int rr = wr * 64 + i * 16 + l16;
        af[i] = *(const f16x8*)&As[cur][rr][((ks * 4 + quad) ^ (rr & 7)) << 3];
      }
#pragma unroll
      for (int j = 0; j < 4; j++) {
        int rr = wc * 64 + j * 16 + l16;
        bf[j] = *(const f16x8*)&Bs[cur][rr][((ks * 4 + quad) ^ (rr & 7)) << 3];
      }
#pragma unroll
      for (int i = 0; i < 4; i++)
#pragma unroll
        for (int j = 0; j < 4; j++)
          acc[i][j] = __builtin_amdgcn_mfma_f32_16x16x32_f16(af[i], bf[j], acc[i][j], 0, 0, 0);
    }
  }

  const int fbase = col0 + wc * 64;
#pragma unroll
  for (int i = 0; i < 4; i++) {
    int n = row0 + wr * 64 + i * 16 + quad * 4;
    int b = n >> 11, nn = n & (SEQ - 1);
#pragma unroll
    for (int j = 0; j < 4; j++) {
      int f = fbase + j * 16 + l16;
      if (col0 < 1536) {
        float* dst = (col0 < 768) ? qT : kT;
        int fo = (col0 < 768) ? f : f - 768;
        *(f32x4*)&dst[((size_t)(b * 768 + fo)) * SEQ + nn] = acc[i][j];
      } else {
        int fo = f - 1536;
        int h = fo >> 6, d = fo & 63;
        int bh = b * NH + h;
        int chn = nn >> 6, cw = (nn & 63) >> 3, sub = nn & 7;
        f16x4 hv;
#pragma unroll
        for (int r = 0; r < 4; r++) hv[r] = (half_t)acc[i][j][r];
        *(f16x4*)&vb[((((size_t)bh * 32 + chn) * 64 + d) << 6) +
                     (((cw ^ (d & 7)) << 3) + sub)] = hv;
      }
    }
  }
}

// ---------------------------------------------------------------------------
// Kernel 2: spectral filter. Forward DIF -> pointwise even filter at bitrev
// positions -> inverse DIT. Q output pre-scaled by 0.125*log2(e).
// ---------------------------------------------------------------------------
__device__ __forceinline__ void fft2048_dif_fwd(float* re, float* im, int tid) {
  for (int M = 2048; M >= 8; M >>= 2) {
    const int q = M >> 2;
    const float ang = -6.283185307179586f / (float)M;
#pragma unroll 2
    for (int g = tid; g < 512; g += 256) {
      int j = g & (q - 1);
      int base = ((g & ~(q - 1)) << 2) | j;
      float s1, c1;
      __sincosf(ang * (float)j, &s1, &c1);
      float c2 = c1 * c1 - s1 * s1, s2 = 2.0f * c1 * s1;
      float Ar = re[base],         Ai = im[base];
      float Br = re[base + q],     Bi = im[base + q];
      float Cr = re[base + 2*q],   Ci = im[base + 2*q];
      float Dr = re[base + 3*q],   Di = im[base + 3*q];
      float A1r = Ar + Cr, A1i = Ai + Ci;
      float t1r = Ar - Cr, t1i = Ai - Ci;
      float C1r = c1 * t1r - s1 * t1i, C1i = c1 * t1i + s1 * t1r;
      float B1r = Br + Dr, B1i = Bi + Di;
      float t2r = Br - Dr, t2i = Bi - Di;
      float u2r = c1 * t2r - s1 * t2i, u2i = c1 * t2i + s1 * t2r;
      float D1r = u2i, D1i = -u2r;
      re[base]         = A1r + B1r; im[base]         = A1i + B1i;
      float t3r = A1r - B1r, t3i = A1i - B1i;
      re[base + q]     = c2 * t3r - s2 * t3i;
      im[base + q]     = c2 * t3i + s2 * t3r;
      re[base + 2*q]   = C1r + D1r; im[base + 2*q]   = C1i + D1i;
      float t4r = C1r - D1r, t4i = C1i - D1i;
      re[base + 3*q]   = c2 * t4r - s2 * t4i;
      im[base + 3*q]   = c2 * t4i + s2 * t4r;
    }
    __syncthreads();
  }
#pragma unroll 2
  for (int i = tid; i < 1024; i += 256) {
    float ar = re[2*i], ai = im[2*i], br = re[2*i+1], bi = im[2*i+1];
    re[2*i]   = ar + br; im[2*i]   = ai + bi;
    re[2*i+1] = ar - br; im[2*i+1] = ai - bi;
  }
  __syncthreads();
}

__device__ __forceinline__ void fft2048_dit_inv(float* re, float* im, int tid) {
  for (int L = 2; L <= 512; L <<= 2) {
    const int h = L >> 1;
    const float ang = 3.14159265358979f / (float)L;
#pragma unroll 2
    for (int g = tid; g < SEQ / 4; g += 256) {
      int p = g & (h - 1);
      int i0 = ((g & ~(h - 1)) << 2) | p;
      float s2, c2;
      __sincosf(ang * (float)p, &s2, &c2);
      float c1 = c2 * c2 - s2 * s2, s1 = 2.0f * c2 * s2;
      float ar = re[i0],         ai = im[i0];
      float br = re[i0 + h],     bi = im[i0 + h];
      float cr = re[i0 + L],     ci = im[i0 + L];
      float dr = re[i0 + L + h], di = im[i0 + L + h];
      float t1r = c1 * br - s1 * bi, t1i = c1 * bi + s1 * br;
      float a1r = ar + t1r, a1i = ai + t1i;
      float b1r = ar - t1r, b1i = ai - t1i;
      float t2r = c1 * dr - s1 * di, t2i = c1 * di + s1 * dr;
      float e1r = cr + t2r, e1i = ci + t2i;
      float d1r = cr - t2r, d1i = ci - t2i;
      float ur = c2 * e1r - s2 * e1i, ui = c2 * e1i + s2 * e1r;
      float vr = c2 * d1r - s2 * d1i, vi = c2 * d1i + s2 * d1r;
      float wr = -vi, wi = vr;
      re[i0]         = a1r + ur; im[i0]         = a1i + ui;
      re[i0 + L]     = a1r - ur; im[i0 + L]     = a1i - ui;
      re[i0 + h]     = b1r + wr; im[i0 + h]     = b1i + wi;
      re[i0 + L + h] = b1r - wr; im[i0 + L + h] = b1i - wi;
    }
    __syncthreads();
  }
  {
    const float ang = 6.283185307179586f / 2048.0f;
#pragma unroll 2
    for (int j = tid; j < 1024; j += 256) {
      float s, c;
      __sincosf(ang * (float)j, &s, &c);
      float x0r = re[j], x0i = im[j], x1r = re[j + 1024], x1i = im[j + 1024];
      float tr = c * x1r - s * x1i, ti = c * x1i + s * x1r;
      re[j] = x0r + tr;        im[j] = x0i + ti;
      re[j + 1024] = x0r - tr; im[j + 1024] = x0i - ti;
    }
    __syncthreads();
  }
}

__global__ __launch_bounds__(256) void fft_filter(
    const float* __restrict__ qT, const float* __restrict__ kT,
    half_t* __restrict__ qh, half_t* __restrict__ kh,
    const float* __restrict__ freq_params) {
  __shared__ float re[SEQ];
  __shared__ float im[SEQ];
  const int tid = threadIdx.x;
  const int idx = blockIdx.x;
  const int h = (idx >> 6) % NH;
  const float* qrow = qT + (size_t)idx * SEQ;
  const float* krow = kT + (size_t)idx * SEQ;

  for (int n = tid; n < SEQ; n += 256) { re[n] = qrow[n]; im[n] = krow[n]; }
  __syncthreads();
  fft2048_dif_fwd(re, im, tid);

  const float fp = freq_params[h];
  const float sig = 1.0f / (1.0f + __expf(-fp));
  const float cutoff = floorf((float)SEQ * sig);

#pragma unroll 2
  for (int p = tid; p < SEQ; p += 256) {
    int n = (int)(__brev((unsigned)p) >> 21);
    int m = (SEQ - n) & (SEQ - 1);
    float r1 = (float)n - cutoff;
    float r2 = (float)m - cutoff;
    float A1 = (r1 >= 0.0f) ? __expf(-r1 * (1.0f / 512.0f)) : 1.0f;
    float A2 = (r2 >= 0.0f) ? __expf(-r2 * (1.0f / 512.0f)) : 1.0f;
    float Ae = 0.5f * (A1 + A2);
    re[p] *= Ae; im[p] *= Ae;
  }
  __syncthreads();

  fft2048_dit_inv(re, im, tid);

  const float invq = (1.0f / (float)SEQ) * 0.18033688011112042f;  // /N * 0.125*log2e
  const float inv = 1.0f / (float)SEQ;
  half_t* qo = qh + (size_t)idx * SEQ;
  half_t* ko = kh + (size_t)idx * SEQ;
  for (int n = tid; n < SEQ; n += 256) {
    qo[n] = (half_t)(re[n] * invq);
    ko[n] = (half_t)(im[n] * inv);
  }
}

// ---------------------------------------------------------------------------
// Kernel 3: transpose K: fp16 d-major -> n-major with chunk XOR swizzle.
// ---------------------------------------------------------------------------
__global__ __launch_bounds__(256) void transpose_k16(
    const half_t* __restrict__ kh, half_t* __restrict__ kA) {
  __shared__ half_t tl[64][65];
  const int t = threadIdx.x;
  const int N0 = blockIdx.x * 64;
  const int bh = blockIdx.y;
#pragma unroll
  for (int i = 0; i < 2; i++) {
    int idx = i * 256 + t;
    int d = idx >> 3, n8 = (idx & 7) << 3;
    f16x8 v = *(const f16x8*)&kh[((size_t)(bh * 64 + d)) * SEQ + N0 + n8];
#pragma unroll
    for (int j = 0; j < 8; j++) tl[d][n8 + j] = v[j];
  }
  __syncthreads();
#pragma unroll
  for (int i = 0; i < 2; i++) {
    int idx = i * 256 + t;
    int nl = idx >> 3, chunk = idx & 7;
    f16x8 v;
#pragma unroll
    for (int j = 0; j < 8; j++) v[j] = tl[chunk * 8 + j][nl];
    *(f16x8*)&kA[((size_t)(bh * SEQ + N0 + nl)) * 64 + (chunk ^ (nl & 7)) * 8] = v;
  }
}

// ---------------------------------------------------------------------------
// Kernel 4: attention v9. 128 q-rows per block (2 subtiles/wave) so K/V LDS
// fragment reads are amortized 2x; grid 768 (16 qt x 24 bh x 2 mh).
// Raw v_exp_f32 (scale folded into q_h, shift dropped), pkrtz cvt, K/V DMA
// double-buffered, one barrier per chunk, L row-sums on the MFMA pipe.
// ---------------------------------------------------------------------------
__global__ __launch_bounds__(256) void attention_v9(
    const half_t* __restrict__ q_h, const half_t* __restrict__ kA,
    const half_t* __restrict__ vb, float* __restrict__ part0,
    float* __restrict__ part1, float* __restrict__ Lp0,
    float* __restrict__ Lp1) {
  __shared__ half_t ks[2][64][64];
  __shared__ half_t vs[2][64][64];
  const int t = threadIdx.x;
  const int lane = t & 63, wave = t >> 6;
  const int quad = lane >> 4, l16 = lane & 15;
  const int id = blockIdx.x;
  const int bh = (id & 7) * 3 + ((id >> 3) % 3);   // 3 bh per XCD
  const int rest = id / 24;                        // 0..31
  const int qt = rest >> 1, mh = rest & 1;
  const int N0 = qt * 128;
  float* part = mh ? part1 : part0;
  float* Lp = mh ? Lp1 : Lp0;
  const half_t* kbase = kA + ((size_t)bh * SEQ + mh * 1024) * 64;
  const half_t* vbase = vb + (((size_t)bh * 32 + mh * 16) << 12);
  const half_t* qb = q_h + (size_t)bh * 64 * SEQ;

  // Q fragments gathered from d-major (B-frag: n on lanes, d in regs)
  f16x8 qlo[2], qhi[2];
#pragma unroll
  for (int u = 0; u < 2; u++) {
    int n = N0 + wave * 32 + u * 16 + l16;
#pragma unroll
    for (int e = 0; e < 8; e++) {
      qlo[u][e] = qb[(size_t)(quad * 8 + e) * SEQ + n];
      qhi[u][e] = qb[(size_t)(32 + quad * 8 + e) * SEQ + n];
    }
  }

  // prologue: DMA chunk 0 into buffer 0
#pragma unroll
  for (int i = 0; i < 2; i++) {
    int ins = wave * 2 + i;
    dma16(kbase + ins * 512 + lane * 8, &ks[0][ins * 8][0]);
    dma16(vbase + ins * 512 + lane * 8, &vs[0][ins * 8][0]);
  }

  f32x4 acc[2][4] = {};
  f32x4 accL[2] = {};
  f16x4 ones;
  ones[0] = (half_t)1.0f; ones[1] = (half_t)1.0f;
  ones[2] = (half_t)1.0f; ones[3] = (half_t)1.0f;

  for (int c = 0; c < 16; c++) {
    const int cur = c & 1;
    __syncthreads();

    if (c < 15) {
      const int cn = c + 1;
#pragma unroll
      for (int i = 0; i < 2; i++) {
        int ins = wave * 2 + i;
        dma16(kbase + (size_t)cn * 4096 + ins * 512 + lane * 8,
              &ks[1 - cur][ins * 8][0]);
        dma16(vbase + (size_t)cn * 4096 + ins * 512 + lane * 8,
              &vs[1 - cur][ins * 8][0]);
      }
    }

    // QK^T (S^T layout) + exp2; K fragments shared across both q-subtiles
    f16x4 pf[2][4];
#pragma unroll
    for (int j = 0; j < 4; j++) {
      int row = j * 16 + l16;
      int sw = row & 7;
      f16x8 klo = *(const f16x8*)&ks[cur][row][(quad ^ sw) * 8];
      f16x8 khi = *(const f16x8*)&ks[cur][row][((quad + 4) ^ sw) * 8];
#pragma unroll
      for (int u = 0; u < 2; u++) {
        f32x4 s = {};
        s = __builtin_amdgcn_mfma_f32_16x16x32_f16(klo, qlo[u], s, 0, 0, 0);
        s = __builtin_amdgcn_mfma_f32_16x16x32_f16(khi, qhi[u], s, 0, 0, 0);
        float e0 = __builtin_amdgcn_exp2f(s[0]);
        float e1 = __builtin_amdgcn_exp2f(s[1]);
        float e2 = __builtin_amdgcn_exp2f(s[2]);
        float e3 = __builtin_amdgcn_exp2f(s[3]);
        auto plo = __builtin_amdgcn_cvt_pkrtz(e0, e1);
        auto phi = __builtin_amdgcn_cvt_pkrtz(e2, e3);
        pf[u][j][0] = (half_t)plo[0]; pf[u][j][1] = (half_t)plo[1];
        pf[u][j][2] = (half_t)phi[0]; pf[u][j][3] = (half_t)phi[1];
      }
    }

    // L on MFMA pipe + PV; V fragments shared across both q-subtiles
#pragma unroll
    for (int j = 0; j < 4; j++) {
      accL[0] = __builtin_amdgcn_mfma_f32_16x16x16f16(pf[0][j], ones, accL[0], 0, 0, 0);
      accL[1] = __builtin_amdgcn_mfma_f32_16x16x16f16(pf[1][j], ones, accL[1], 0, 0, 0);
#pragma unroll
      for (int dt = 0; dt < 4; dt++) {
        int d = dt * 16 + l16;
        int cc = ((2 * j + (quad >> 1)) ^ (d & 7));
        f16x4 bv = *(const f16x4*)&vs[cur][d][cc * 8 + (quad & 1) * 4];
        acc[0][dt] = __builtin_amdgcn_mfma_f32_16x16x16f16(pf[0][j], bv, acc[0][dt], 0, 0, 0);
        acc[1][dt] = __builtin_amdgcn_mfma_f32_16x16x16f16(pf[1][j], bv, acc[1][dt], 0, 0, 0);
      }
    }
  }

#pragma unroll
  for (int u = 0; u < 2; u++) {
    if (l16 == 0) {
#pragma unroll
      for (int r = 0; r < 4; r++)
        Lp[(size_t)bh * SEQ + N0 + wave * 32 + u * 16 + quad * 4 + r] = accL[u][r];
    }
#pragma unroll
    for (int dt = 0; dt < 4; dt++) {
#pragma unroll
      for (int r = 0; r < 4; r++) {
        int n = N0 + wave * 32 + u * 16 + quad * 4 + r;
        part[((size_t)bh * SEQ + n) * 64 + dt * 16 + l16] = acc[u][dt][r];
      }
    }
  }
}

// ---------------------------------------------------------------------------
// Kernel 5: combine partials -> ao (fp16, (B,N,H,D) row-major).
// ---------------------------------------------------------------------------
__global__ __launch_bounds__(256) void combine_o(
    const float* __restrict__ p0, const float* __restrict__ p1,
    const float* __restrict__ L0, const float* __restrict__ L1,
    half_t* __restrict__ ao) {
  int idx = blockIdx.x * 256 + threadIdx.x;
  int row = idx >> 4;
  int d = (idx & 15) << 2;
  f32x4 a = *(const f32x4*)&p0[(size_t)row * 64 + d];
  f32x4 b = *(const f32x4*)&p1[(size_t)row * 64 + d];
  float inv = 1.0f / (L0[row] + L1[row]);
  int bh = row >> 11, n = row & (SEQ - 1);
  int bb = bh / NH, h = bh % NH;
  f16x4 o;
#pragma unroll
  for (int r = 0; r < 4; r++) o[r] = (half_t)((a[r] + b[r]) * inv);
  *(f16x4*)&ao[((size_t)(bb * SEQ + n)) * DIM + h * 64 + d] = o;
}

// ---------------------------------------------------------------------------
// Kernel 6: proj GEMM, fp16 inputs (plain layouts), fp32 out + bias.
// ---------------------------------------------------------------------------
__global__ __launch_bounds__(256) void gemm_proj_f16(
    const half_t* __restrict__ ao, const half_t* __restrict__ w,
    const float* __restrict__ bias, float* __restrict__ out) {
  __shared__ half_t As[128][64];
  __shared__ half_t Bs[128][64];
  const int tid = threadIdx.x;
  const int lane = tid & 63, wave = tid >> 6;
  const int quad = lane >> 4, l16 = lane & 15;
  const int wr = wave >> 1, wc = wave & 1;
  const int row0 = blockIdx.y * 128;
  const int col0 = blockIdx.x * 128;
  const int srow = tid >> 3;
  const int schk = tid & 7;

  f32x4 acc[4][4] = {};

  for (int k0 = 0; k0 < DIM; k0 += 64) {
    f16x8 av[4], bv[4];
#pragma unroll
    for (int p = 0; p < 4; p++) {
      av[p] = *(const f16x8*)&ao[(size_t)(row0 + srow + p * 32) * DIM + k0 + schk * 8];
      bv[p] = *(const f16x8*)&w[(size_t)(col0 + srow + p * 32) * DIM + k0 + schk * 8];
    }
    __syncthreads();
#pragma unroll
    for (int p = 0; p < 4; p++) {
      int r = srow + p * 32;
      int cs = ((schk ^ (r & 7)) << 3);
      *(f16x8*)&As[r][cs] = av[p];
      *(f16x8*)&Bs[r][cs] = bv[p];
    }
    __syncthreads();
#pragma unroll
    for (int ks = 0; ks < 2; ks++) {
      f16x8 af[4], bf[4];
#pragma unroll
      for (int i = 0; i < 4; i++) {
        int rr = wr * 64 + i * 16 + l16;
        af[i] = *(const f16x8*)&As[rr][((ks * 4 + quad) ^ (rr & 7)) << 3];
      }
#pragma unroll
      for (int j = 0; j < 4; j++) {
        int rr = wc * 64 + j * 16 + l16;
        bf[j] = *(const f16x8*)&Bs[rr][((ks * 4 + quad) ^ (rr & 7)) << 3];
      }
#pragma unroll
      for (int i = 0; i < 4; i++)
#pragma unroll
        for (int j = 0; j < 4; j++)
          acc[i][j] = __builtin_amdgcn_mfma_f32_16x16x32_f16(af[i], bf[j], acc[i][j], 0, 0, 0);
    }
  }

#pragma unroll
  for (int i = 0; i < 4; i++) {
    int m = row0 + wr * 64 + i * 16 + quad * 4;
#pragma unroll
    for (int j = 0; j < 4; j++) {
      int f = col0 + wc * 64 + j * 16 + l16;
      float bj = bias[f];
#pragma unroll
      for (int r = 0; r < 4; r++)
        out[(size_t)(m + r) * DIM + f] = acc[i][j][r] + bj;
    }
  }
}

// ---------------------------------------------------------------------------
extern "C" void kernel_launch(void* const* d_in, const int* in_sizes, int n_in,
                              void* d_out, int out_size, void* d_ws, size_t ws_size,
                              hipStream_t stream) {
  (void)in_sizes; (void)n_in; (void)out_size; (void)ws_size;
  const float* x      = (const float*)d_in[0];
  const float* qkv_w  = (const float*)d_in[1];
  const float* proj_w = (const float*)d_in[2];
  const float* proj_b = (const float*)d_in[3];
  const float* freq   = (const float*)d_in[4];
  float* out = (float*)d_out;
  char* ws = (char*)d_ws;

  // Workspace (bytes):
  //  wp16 [0, 1179648)                   plain fp16 proj_w
  //  qT   [1179648, 13762560)  fp32  ->  part0 after fft
  //  kT   [13762560, 26345472) fp32  ->  part1 after fft
  //  v_blk[26345472, 32636928) fp16      chunked+swizzled
  //  x16  [32636928, 38928384) fp16 swz -> k_h after gemm
  //  w16  [38928384, 42467328) fp16 swz -> Lp0/Lp1 after gemm
  //  q_h  [42467328, 48758784) fp16      (d-major, q pre-scaled) -> ao
  //  kA (n-major swizzled): d_out[0 : 6291456) — overwritten by proj at end
  half_t* wp16 = (half_t*)(ws);
  float*  qT   = (float*)(ws + 1179648);
  float*  kT   = (float*)(ws + 13762560);
  half_t* v_b  = (half_t*)(ws + 26345472);
  half_t* x16  = (half_t*)(ws + 32636928);
  half_t* w16  = (half_t*)(ws + 38928384);
  half_t* q_h  = (half_t*)(ws + 42467328);
  half_t* k_h  = (half_t*)(ws + 32636928);
  float*  part0 = (float*)(ws + 1179648);
  float*  part1 = (float*)(ws + 13762560);
  float*  Lp0  = (float*)(ws + 38928384);
  float*  Lp1  = (float*)(ws + 38928384 + 196608);
  half_t* ao   = (half_t*)(ws + 42467328);
  half_t* kA   = (half_t*)d_out;

  cvt_f32_f16<<<5376, 256, 0, stream>>>(x, qkv_w, proj_w, x16, w16, wp16);
  gemm_qkv_f16<<<dim3(18, 32), 256, 0, stream>>>(x16, w16, qT, kT, v_b);
  fft_filter<<<1536, 256, 0, stream>>>(qT, kT, q_h, k_h, freq);
  transpose_k16<<<dim3(32, 24), 256, 0, stream>>>(k_h, kA);
  attention_v9<<<768, 256, 0, stream>>>(q_h, kA, v_b, part0, part1, Lp0, Lp1);
  combine_o<<<3072, 256, 0, stream>>>(part0, part1, Lp0, Lp1, ao);
  gemm_proj_f16<<<dim3(6, 32), 256, 0, stream>>>(ao, wp16, proj_b, out);
}